// Round 9
// baseline (250.562 us; speedup 1.0000x reference)
//
#include <hip/hip_runtime.h>
#include <cstddef>

// Problem constants (b=4, ch=128, h=w=64)
#define B_      4
#define C_      128
#define L_      4096      // h*w
#define DIN     256       // expand*ch
#define NH      4         // heads
#define HD      64        // head dim
#define DS      64        // d_state
#define CONVCH  384       // din + 2*ds
#define DPROJ   644       // 2*din + 2*ds + nh
#define CHUNK   64
#define NCHUNK  64        // L_/CHUNK

typedef short bf16x8 __attribute__((ext_vector_type(8)));
typedef float floatx16 __attribute__((ext_vector_type(16)));

__device__ __forceinline__ float siluf(float v) { return v / (1.f + __expf(-v)); }

__device__ __forceinline__ ushort f2bf(float v) {
  unsigned u = __float_as_uint(v);
  unsigned r = (u + 0x7fff + ((u >> 16) & 1)) >> 16;
  return (ushort)r;
}
__device__ __forceinline__ float bf2f(ushort h) {
  return __uint_as_float((unsigned)h << 16);
}

// split 8 fp32 into hi/lo bf16x8 fragments (3-term split-bf16 scheme)
__device__ __forceinline__ void split8(float4 v0, float4 v1, bf16x8& hi, bf16x8& lo) {
  float f[8] = {v0.x, v0.y, v0.z, v0.w, v1.x, v1.y, v1.z, v1.w};
#pragma unroll
  for (int j = 0; j < 8; ++j) {
    ushort h = f2bf(f[j]);
    hi[j] = (short)h;
    lo[j] = (short)f2bf(f[j] - bf2f(h));
  }
}

// ---------------------------------------------------------------------------
// wprep_all: fused weight prep — ipw (blocks 0..175), opw (176..303),
// fw1 conv weights (304..431), fw2 conv weights (432..559). Tap-major conv
// weights: Wt[((tap*8 + kk)*4 + cb)*512 + l*8 + j], k = ci, m = co.
__global__ __launch_bounds__(256) void wprep_all(
    const float* __restrict__ ipw, ushort* __restrict__ Bh, ushort* __restrict__ Bl,
    const float* __restrict__ opw, ushort* __restrict__ Oh, ushort* __restrict__ Ol,
    const float* __restrict__ fw1, ushort* __restrict__ Wt1,
    const float* __restrict__ fw2, ushort* __restrict__ Wt2) {
  int bi = blockIdx.x;
  int t = threadIdx.x;
  if (bi < 176) {
    int e = bi * 256 + t;
    int d = e >> 6;
    int c0 = (e & 63) * 2;
    int kk = c0 >> 4;
    int l = (d & 31) + 32 * ((c0 & 15) >> 3);
    int j = c0 & 7;
    size_t off = (((size_t)(d >> 5)) * 8 + kk) * 512 + l * 8 + j;
    float v0 = d < 644 ? ipw[(size_t)d * 128 + c0] : 0.f;
    float v1 = d < 644 ? ipw[(size_t)d * 128 + c0 + 1] : 0.f;
    ushort h0 = f2bf(v0), h1 = f2bf(v1);
    *(unsigned*)(Bh + off) = (unsigned)h0 | ((unsigned)h1 << 16);
    *(unsigned*)(Bl + off) = (unsigned)f2bf(v0 - bf2f(h0)) |
                             ((unsigned)f2bf(v1 - bf2f(h1)) << 16);
  } else if (bi < 304) {
    int e = (bi - 176) * 256 + t;  // 0..32767
    int d = e >> 8;
    int c = e & 255;
    size_t f = ((size_t)(d >> 5) * 16 + (c >> 4)) * 512 +
               ((d & 31) + 32 * ((c & 15) >> 3)) * 8 + (c & 7);
    float v = opw[(size_t)d * 256 + c];
    ushort h = f2bf(v);
    Oh[f] = h;
    Ol[f] = f2bf(v - bf2f(h));
  } else {
    const float* fw = bi < 432 ? fw1 : fw2;
    ushort* Wt = bi < 432 ? Wt1 : Wt2;
    int co = (bi - 304) & 127;  // 0..127
    int cb = co >> 5;
    for (int e = t; e < 1152; e += 256) {
      int tap = e >> 7;          // 0..8
      int ci = e & 127;          // 0..127
      int kk = ci >> 4, k16 = ci & 15;
      int l = (co & 31) + 32 * (k16 >> 3);
      int off = ((tap * 8 + kk) * 4 + cb) * 512 + l * 8 + (k16 & 7);
      Wt[off] = f2bf(fw[(size_t)co * 1152 + ci * 9 + tap]);
    }
  }
}

// ---------------------------------------------------------------------------
// ln_gemm1 v2: fused LayerNorm + in_proj GEMM, 32-px tiles for 2+ blocks/CU.
// grid (128, 4), block 512.
__global__ __launch_bounds__(512) void ln_gemm1(
    const float* __restrict__ noisy, const float* __restrict__ gamma,
    const float* __restrict__ beta,
    const ushort* __restrict__ Bh, const ushort* __restrict__ Bl,
    float* __restrict__ ZX) {
  int row = blockIdx.x, b = blockIdx.y;   // row = 32-px tile index (0..127)
  int t = threadIdx.x;                    // 0..511
  __shared__ float tile[32 * 129];              // 16.5 KB
  __shared__ float ps[16][32], pq[16][32];      // 4 KB
  __shared__ float smu[32], srs[32];
  __shared__ __align__(16) ushort AhL[4096];    // 8 KB
  __shared__ __align__(16) ushort AlL[4096];    // 8 KB
  int px = t & 31, cg = t >> 5;  // cg 0..15
  float s = 0.f, s2 = 0.f;
  const float* src = noisy + ((size_t)b * C_) * L_ + row * 32;
  for (int i = 0; i < 8; ++i) {
    int c = cg * 8 + i;
    float v = src[(size_t)c * L_ + px];
    tile[px * 129 + c] = v;
    s += v; s2 += v * v;
  }
  ps[cg][px] = s; pq[cg][px] = s2;
  __syncthreads();
  if (t < 32) {
    float a = 0.f, qq = 0.f;
#pragma unroll
    for (int g = 0; g < 16; ++g) { a += ps[g][t]; qq += pq[g][t]; }
    float mu = a * (1.f / 128.f);
    float var = qq * (1.f / 128.f) - mu * mu;
    smu[t] = mu;
    srs[t] = rsqrtf(var + 1e-5f);
  }
  __syncthreads();
  for (int idx = t; idx < 2048; idx += 512) {
    int p2 = idx >> 6;       // pixel within tile (0..31)
    int c0 = (idx & 63) * 2; // channel pair
    float v0 = (tile[p2 * 129 + c0] - smu[p2]) * srs[p2] * gamma[c0] + beta[c0];
    float v1 = (tile[p2 * 129 + c0 + 1] - smu[p2]) * srs[p2] * gamma[c0 + 1] + beta[c0 + 1];
    int kk = c0 >> 4;
    int l = p2 + 32 * ((c0 & 15) >> 3);
    int j = c0 & 7;  // even
    int off = kk * 512 + l * 8 + j;
    ushort h0 = f2bf(v0), h1 = f2bf(v1);
    *(unsigned*)(AhL + off) = (unsigned)h0 | ((unsigned)h1 << 16);
    *(unsigned*)(AlL + off) = (unsigned)f2bf(v0 - bf2f(h0)) |
                              ((unsigned)f2bf(v1 - bf2f(h1)) << 16);
  }
  __syncthreads();
  int wv = t >> 6, lane = t & 63;
  int db = wv & 1, bq = wv >> 1;  // bq 0..3
  int rowadd = 4 * (lane >> 5);
  for (int bn = bq; bn < 11; bn += 4) {
    floatx16 acc;
#pragma unroll
    for (int i = 0; i < 16; ++i) acc[i] = 0.f;
    size_t bbase = ((size_t)(bn * 2 + db) * 8) * 64 + lane;
    const bf16x8* pBh = (const bf16x8*)Bh + bbase;
    const bf16x8* pBl = (const bf16x8*)Bl + bbase;
#pragma unroll
    for (int kk = 0; kk < 8; ++kk) {
      bf16x8 ah = *(const bf16x8*)(AhL + kk * 512 + lane * 8);
      bf16x8 al = *(const bf16x8*)(AlL + kk * 512 + lane * 8);
      bf16x8 bh = pBh[kk * 64];
      bf16x8 bl = pBl[kk * 64];
      acc = __builtin_amdgcn_mfma_f32_32x32x16_bf16(ah, bh, acc, 0, 0, 0);
      acc = __builtin_amdgcn_mfma_f32_32x32x16_bf16(al, bh, acc, 0, 0, 0);
      acc = __builtin_amdgcn_mfma_f32_32x32x16_bf16(ah, bl, acc, 0, 0, 0);
    }
    int d = bn * 64 + db * 32 + (lane & 31);
    if (d < 644) {
#pragma unroll
      for (int r = 0; r < 16; ++r) {
        int rowm = (r & 3) + 8 * (r >> 2) + rowadd;
        int pix = row * 32 + rowm;
        ZX[((size_t)(b * L_ + pix)) * DPROJ + d] = acc[r];
      }
    }
  }
}

// ---------------------------------------------------------------------------
// K3: depthwise causal conv1d (k=5) + bias + silu; 16 outputs/thread.
__global__ __launch_bounds__(384) void conv1d_silu(
    const float* __restrict__ ZX, const float* __restrict__ cw,
    const float* __restrict__ cb, float* __restrict__ XBC) {
  int ch = threadIdx.x;
  int l0 = blockIdx.x * 16, b = blockIdx.y;
  const float* base = ZX + ((size_t)b * L_) * DPROJ + DIN + ch;
  float w0 = cw[ch * 5], w1 = cw[ch * 5 + 1], w2 = cw[ch * 5 + 2],
        w3 = cw[ch * 5 + 3], w4 = cw[ch * 5 + 4];
  float bias = cb[ch];
  float win[20];
#pragma unroll
  for (int i = 0; i < 20; ++i) {
    int ll = l0 - 4 + i;
    win[i] = ll >= 0 ? base[(size_t)ll * DPROJ] : 0.f;
  }
  float* dst = XBC + ((size_t)(b * L_ + l0)) * CONVCH + ch;
#pragma unroll
  for (int j = 0; j < 16; ++j) {
    float acc = bias + w0 * win[j] + w1 * win[j + 1] + w2 * win[j + 2] +
                w3 * win[j + 3] + w4 * win[j + 4];
    dst[(size_t)j * CONVCH] = siluf(acc);
  }
}

// ---------------------------------------------------------------------------
// K5: scan pass A — LDS-broadcast staging. grid (NCHUNK, NH, B_), block 256.
#define UPDA(k, B4, C4) \
  st[4*k+0] = st[4*k+0]*da + cf*B4.x; y0 += st[4*k+0]*C4.x; \
  st[4*k+1] = st[4*k+1]*da + cf*B4.y; y1 += st[4*k+1]*C4.y; \
  st[4*k+2] = st[4*k+2]*da + cf*B4.z; y2 += st[4*k+2]*C4.z; \
  st[4*k+3] = st[4*k+3]*da + cf*B4.w; y3 += st[4*k+3]*C4.w;

__global__ __launch_bounds__(256, 4) void scan_passA(
    const float* __restrict__ XBC, const float* __restrict__ ZX,
    const float* __restrict__ dt_bias, const float* __restrict__ A_log,
    float* __restrict__ YL, float* __restrict__ SC, float* __restrict__ PC,
    float* __restrict__ CUM) {
  int chunk = blockIdx.x, h = blockIdx.y, b = blockIdx.z;
  int t = threadIdx.x;
  int p = t >> 2, q = t & 3;
  int bh = b * NH + h;
  __shared__ float sdt[CHUNK], sda[CHUNK];
  __shared__ float sB[32][64];
  __shared__ float sCc[32][64];
  __shared__ float sx[32][64];
  if (t < CHUNK) {
    int l = chunk * CHUNK + t;
    float v = ZX[((size_t)(b * L_ + l)) * DPROJ + 640 + h] + dt_bias[h];
    float dt = v > 20.f ? v : log1pf(expf(v));
    sdt[t] = dt;
    sda[t] = expf(dt * -expf(A_log[h]));
  }
  size_t rowbase = ((size_t)b * L_ + (size_t)chunk * CHUNK) * CONVCH;
  float* __restrict__ yl = YL + ((size_t)b * L_ + (size_t)chunk * CHUNK) * DIN + h * HD + p;
  float* __restrict__ cumout = CUM + (size_t)bh * L_ + chunk * CHUNK;
  float st[16];
#pragma unroll
  for (int j = 0; j < 16; ++j) st[j] = 0.f;
  float cum = 1.f;
  for (int half = 0; half < 2; ++half) {
    __syncthreads();   // protects sdt (half 0) / prior-half LDS (half 1)
#pragma unroll
    for (int i = 0; i < 2; ++i) {
      int e = t + i * 256;                 // 0..511
      int row = e >> 4, c4 = (e & 15) * 4;
      const float* gsrc = XBC + rowbase + (size_t)(half * 32 + row) * CONVCH;
      *(float4*)&sB[row][c4]  = *(const float4*)(gsrc + DIN + c4);
      *(float4*)&sCc[row][c4] = *(const float4*)(gsrc + DIN + DS + c4);
      *(float4*)&sx[row][c4]  = *(const float4*)(gsrc + h * HD + c4);
    }
    __syncthreads();
#pragma unroll 4
    for (int tl = 0; tl < 32; ++tl) {
      int tg = half * 32 + tl;
      float da = sda[tg], dtv = sdt[tg];
      float x = sx[tl][p];
      float cf = dtv * x;
      const float4* br = (const float4*)&sB[tl][q * 16];
      const float4* cr = (const float4*)&sCc[tl][q * 16];
      float4 B0 = br[0], B1 = br[1], B2 = br[2], B3 = br[3];
      float4 C0 = cr[0], C1 = cr[1], C2 = cr[2], C3 = cr[3];
      float y0 = 0.f, y1 = 0.f, y2 = 0.f, y3 = 0.f;
      UPDA(0, B0, C0) UPDA(1, B1, C1) UPDA(2, B2, C2) UPDA(3, B3, C3)
      float y = (y0 + y1) + (y2 + y3);
      y += __shfl_xor(y, 1);
      y += __shfl_xor(y, 2);
      cum *= da;
      if (q == 0) yl[(size_t)tg * DIN] = y;
      if (t == 0) cumout[tg] = cum;
    }
  }
  float* scp = SC + ((size_t)bh * NCHUNK + chunk) * 4096 + p * 64 + q * 16;
  *(float4*)(scp + 0)  = make_float4(st[0], st[1], st[2], st[3]);
  *(float4*)(scp + 4)  = make_float4(st[4], st[5], st[6], st[7]);
  *(float4*)(scp + 8)  = make_float4(st[8], st[9], st[10], st[11]);
  *(float4*)(scp + 12) = make_float4(st[12], st[13], st[14], st[15]);
  if (t == 0) PC[bh * NCHUNK + chunk] = cum;
}

// ---------------------------------------------------------------------------
// K6: element-parallel in-place scan over chunks: SC[c] <- exclusive prefix state.
__global__ __launch_bounds__(256) void scan_passB(
    float* __restrict__ SC, const float* __restrict__ PC) {
  int bh = blockIdx.x >> 4;
  int eg = blockIdx.x & 15;
  int e = eg * 256 + threadIdx.x;
  float h = 0.f;
#pragma unroll 8
  for (int c = 0; c < NCHUNK; ++c) {
    size_t idx = ((size_t)bh * NCHUNK + c) * 4096 + e;
    float s = SC[idx];
    float pcv = PC[bh * NCHUNK + c];
    SC[idx] = h;
    h = h * pcv + s;
  }
}

// ---------------------------------------------------------------------------
// passC_gate v3: half-chunk blocks (32 px) for 2 blocks/CU. grid (NCHUNK*2, B_),
// block 512 (8 waves).
__global__ __launch_bounds__(512) void passC_gate(
    const float* __restrict__ XBC, const float* __restrict__ SC,
    const float* __restrict__ CUM, const float* __restrict__ Dp,
    const float* __restrict__ YL, const float* __restrict__ ZX,
    const float* __restrict__ rmsw,
    const ushort* __restrict__ Oh, const ushort* __restrict__ Ol,
    const float* __restrict__ noisy, float* __restrict__ YRES) {
  __shared__ float yt[8192];                     // 32 KB: [32 px][256 ch]
  __shared__ __align__(16) ushort fr[16384];     // 32 KB: C-stage / frags / fp32 tile
  int hc = blockIdx.x, b = blockIdx.y;           // hc = half-chunk (0..127)
  int chunk = hc >> 1;
  int l0 = hc * 32;
  int t = threadIdx.x;                           // 0..511
  int wv = t >> 6, lane = t & 63;
  size_t pix0g = (size_t)b * L_ + l0;
  float* sCcf  = (float*)fr;        // [32 px][16 float4-slots] XOR-swizzled, 8 KB
  float* scumf = sCcf + 2048;       // [4 h][32 px], 0.5 KB

  // --- phase 0a: zreg prefetch, YL->yt, stage C + cum ---
  float4 zr[4];
  {
    int lp = t & 31, slot2 = t >> 5;  // slot2 0..15
#pragma unroll
    for (int it = 0; it < 2; ++it) {
      const float* z = ZX + (pix0g + it * 16 + slot2) * DPROJ;
      zr[it * 2]     = *(const float4*)(z + lp * 4);
      zr[it * 2 + 1] = *(const float4*)(z + 128 + lp * 4);
    }
  }
  for (int i = t; i < 2048; i += 512) {
    *(float4*)&yt[i * 4] = *(const float4*)&YL[pix0g * DIN + (size_t)i * 4];
  }
  {
    int px = t >> 4, slot = t & 15;   // px 0..31
    float4 cv = *(const float4*)(XBC + (pix0g + px) * CONVCH + DIN + DS + slot * 4);
    ((float4*)sCcf)[px * 16 + (slot ^ (px & 7))] = cv;
    if (t < 128) {
      int hh = t >> 5, px2 = t & 31;
      scumf[t] = CUM[((size_t)(b * NH + hh)) * L_ + l0 + px2];
    }
  }
  __syncthreads();

  // --- phase 0b: yt += x * D (skip term) ---
  {
    int px = t >> 4, c4 = (t & 15) * 4;
    const float* xs = XBC + (pix0g + px) * CONVCH;
#pragma unroll
    for (int hh = 0; hh < 4; ++hh) {
      float4 xv = *(const float4*)(xs + hh * HD + c4);
      float dv = Dp[hh];
      float* dst = &yt[px * 256 + hh * 64 + c4];
      dst[0] += xv.x * dv; dst[1] += xv.y * dv;
      dst[2] += xv.z * dv; dst[3] += xv.w * dv;
    }
  }
  __syncthreads();

  // --- phase 1: per-head inter-chunk GEMM Y += (C x S^T) * cum ---
  {
    int h1 = wv >> 1, ptile = wv & 1;
    int arow = lane & 31;             // px row 0..31
    const float* Sb = SC + (((size_t)(b * NH + h1)) * NCHUNK + chunk) * 4096 +
                      (size_t)(ptile * 32 + (lane & 31)) * 64 + (lane >> 5) * 8;
    const float4* av = (const float4*)sCcf + arow * 16;
    int s0 = (lane >> 5) * 2;
    floatx16 acc;
#pragma unroll
    for (int i = 0; i < 16; ++i) acc[i] = 0.f;
#pragma unroll
    for (int kk = 0; kk < 4; ++kk) {
      float4 b0 = *(const float4*)(Sb + kk * 16);
      float4 b1 = *(const float4*)(Sb + kk * 16 + 4);
      int sa = kk * 4 + s0;
      float4 a0 = av[sa ^ (arow & 7)];
      float4 a1 = av[(sa + 1) ^ (arow & 7)];
      bf16x8 ah, al, bh, bl;
      split8(a0, a1, ah, al);
      split8(b0, b1, bh, bl);
      acc = __builtin_amdgcn_mfma_f32_32x32x16_bf16(ah, bh, acc, 0, 0, 0);
      acc = __builtin_amdgcn_mfma_f32_32x32x16_bf16(al, bh, acc, 0, 0, 0);
      acc = __builtin_amdgcn_mfma_f32_32x32x16_bf16(ah, bl, acc, 0, 0, 0);
    }
    int col = h1 * 64 + ptile * 32 + (lane & 31);
    int radd = 4 * (lane >> 5);
#pragma unroll
    for (int r = 0; r < 16; ++r) {
      int px = (r & 3) + 8 * (r >> 2) + radd;   // 0..31
      yt[px * 256 + col] += acc[r] * scumf[h1 * 32 + px];
    }
  }
  __syncthreads();   // yt complete; sCcf dead -> fr reusable as frags

  // --- phase 2: gating + RMSNorm -> bf16 hi/lo frags in fr (z from zr) ---
  ushort* AhL = fr;            // 16 KB
  ushort* AlL = fr + 8192;     // 16 KB
  {
    int lp = t & 31;
    int slot = t >> 5;           // 0..15
    float4 w0 = *(const float4*)(rmsw + lp * 4);
    float4 w1 = *(const float4*)(rmsw + 128 + lp * 4);
#pragma unroll
    for (int it = 0; it < 2; ++it) {
      int pl = it * 16 + slot;   // 0..31
      const float* y = &yt[pl * 256];
      float4 y0 = *(const float4*)(y + lp * 4);
      float4 y1 = *(const float4*)(y + 128 + lp * 4);
      float4 z0 = zr[it * 2];
      float4 z1 = zr[it * 2 + 1];
      float g[8];
      g[0] = y0.x * siluf(z0.x); g[1] = y0.y * siluf(z0.y);
      g[2] = y0.z * siluf(z0.z); g[3] = y0.w * siluf(z0.w);
      g[4] = y1.x * siluf(z1.x); g[5] = y1.y * siluf(z1.y);
      g[6] = y1.z * siluf(z1.z); g[7] = y1.w * siluf(z1.w);
      float ss = 0.f;
#pragma unroll
      for (int j = 0; j < 8; ++j) ss += g[j] * g[j];
      ss += __shfl_xor(ss, 16);
      ss += __shfl_xor(ss, 8);
      ss += __shfl_xor(ss, 4);
      ss += __shfl_xor(ss, 2);
      ss += __shfl_xor(ss, 1);
      float rs = rsqrtf(ss * (1.f / 256.f) + 1e-5f);
      float o[8];
      o[0] = g[0] * rs * w0.x; o[1] = g[1] * rs * w0.y;
      o[2] = g[2] * rs * w0.z; o[3] = g[3] * rs * w0.w;
      o[4] = g[4] * rs * w1.x; o[5] = g[5] * rs * w1.y;
      o[6] = g[6] * rs * w1.z; o[7] = g[7] * rs * w1.w;
#pragma unroll
      for (int grp = 0; grp < 2; ++grp) {
        int d = grp * 128 + lp * 4;
        int off = (d >> 4) * 512 + (pl + 32 * ((d & 15) >> 3)) * 8 + (d & 7);
        ushort h0 = f2bf(o[grp*4+0]), h1 = f2bf(o[grp*4+1]);
        ushort h2 = f2bf(o[grp*4+2]), h3 = f2bf(o[grp*4+3]);
        uint2 hv, lv;
        hv.x = (unsigned)h0 | ((unsigned)h1 << 16);
        hv.y = (unsigned)h2 | ((unsigned)h3 << 16);
        lv.x = (unsigned)f2bf(o[grp*4+0] - bf2f(h0)) | ((unsigned)f2bf(o[grp*4+1] - bf2f(h1)) << 16);
        lv.y = (unsigned)f2bf(o[grp*4+2] - bf2f(h2)) | ((unsigned)f2bf(o[grp*4+3] - bf2f(h3)) << 16);
        *(uint2*)(AhL + off) = hv;
        *(uint2*)(AlL + off) = lv;
      }
    }
  }
  __syncthreads();

  // --- phase 3: out_proj GEMM (waves 0-3; M=32, N=128, K=256) ---
  floatx16 acc;
#pragma unroll
  for (int i = 0; i < 16; ++i) acc[i] = 0.f;
  int bn = wv >> 1, db = wv & 1;
  int rowadd = 4 * (lane >> 5);
  if (wv < 4) {
    const bf16x8* pBh = (const bf16x8*)Oh;
    const bf16x8* pBl = (const bf16x8*)Ol;
    size_t bbase = ((size_t)(bn * 2 + db) * 16) * 64 + lane;
#pragma unroll
    for (int kk = 0; kk < 16; ++kk) {
      bf16x8 ah = *(const bf16x8*)(AhL + kk * 512 + lane * 8);
      bf16x8 al = *(const bf16x8*)(AlL + kk * 512 + lane * 8);
      bf16x8 bh = pBh[bbase + (size_t)kk * 64];
      bf16x8 bl = pBl[bbase + (size_t)kk * 64];
      acc = __builtin_amdgcn_mfma_f32_32x32x16_bf16(ah, bh, acc, 0, 0, 0);
      acc = __builtin_amdgcn_mfma_f32_32x32x16_bf16(al, bh, acc, 0, 0, 0);
      acc = __builtin_amdgcn_mfma_f32_32x32x16_bf16(ah, bl, acc, 0, 0, 0);
    }
  }
  __syncthreads();   // frag reads complete -> fr reusable as fp32 tile

  // --- phase 4: transpose via LDS, residual add, write YRES (b,C,L) ---
  float* tile = (float*)fr;    // 32 px x 129 fp32 = 16.5 KB
  if (wv < 4) {
#pragma unroll
    for (int r = 0; r < 16; ++r) {
      int rowp = (r & 3) + 8 * (r >> 2) + rowadd;     // 0..31
      int col = bn * 64 + db * 32 + (lane & 31);      // 0..127
      tile[rowp * 129 + col] = acc[r];
    }
  }
  __syncthreads();
  for (int idx = t; idx < 4096; idx += 512) {
    int c = idx >> 5, px = idx & 31;
    size_t o = ((size_t)(b * C_ + c)) * L_ + l0 + px;
    YRES[o] = noisy[o] + tile[px * 129 + c];
  }
}

// ---------------------------------------------------------------------------
// conv3x3_direct v2: x-half blocks for 2 blocks/CU overlap (was grid 256 =
// 1 block/CU with serial stage->MFMA phases). Each block stages the FULL
// 3-row x 64-col x 128-ci tile (coalesced lane<->x; duplicate reads are
// L2-absorbed) but computes only 32 x-columns. Bit-identical arithmetic.
// MODE 0: input fp32 (YRES), output bf16 = relu(conv+bias) (FF1).
// MODE 1: input bf16 (FF1), output fp32 = res + relu(conv+bias);
//         grid.z==1 blocks instead copy aux -> out[2M..4M) (folded memcpy).
// grid (128 = y*2+xh, 4 b[, 2]), block 256 (4 waves = cb).
template <int MODE>
__global__ __launch_bounds__(256) void conv3x3_direct(
    const void* __restrict__ inv, const ushort* __restrict__ Wt,
    const float* __restrict__ bias, const float* __restrict__ res,
    void* __restrict__ outv, const float* __restrict__ aux) {
  int bx = blockIdx.x, b = blockIdx.y;
  int t = threadIdx.x;
  if (MODE == 1 && blockIdx.z == 1) {
    // aux passthrough: 524288 float4 over 512 blocks x 256 threads x 4
    const float4* s = (const float4*)aux;
    float4* d = (float4*)((float*)outv + 2097152);
    int base = (b * 128 + bx) * 256 + t;
#pragma unroll
    for (int k = 0; k < 4; ++k) d[base + k * 131072] = s[base + k * 131072];
    return;
  }
  int y = bx >> 1, xh = bx & 1;
  __shared__ __align__(16) ushort lds[3 * 64 * 128];  // 48 KB
  int lane = t & 63;
  int wv = t >> 6;             // 0..3 = cb
  int ry[3];
  ry[0] = y == 0 ? 1 : y - 1;
  ry[1] = y;
  ry[2] = y == 63 ? 62 : y + 1;
  {
    int x = lane;
    for (int u = wv; u < 48; u += 4) {
      int r = u / 16;
      int cib = u % 16;
      int ci0 = cib * 8;
      ushort vals[8];
#pragma unroll
      for (int j = 0; j < 8; ++j) {
        size_t src = ((size_t)(b * C_ + ci0 + j)) * L_ + ry[r] * 64 + x;
        if (MODE == 0) vals[j] = f2bf(((const float*)inv)[src]);
        else           vals[j] = ((const ushort*)inv)[src];
      }
      int idx = (r * 64 + x) * 128 + (cib ^ (x & 15)) * 8;
      *(int4*)&lds[idx] = *(int4*)vals;
    }
  }
  __syncthreads();
  int cb = wv;
  int n = lane & 31, hi = lane >> 5;
  floatx16 acc0, acc1;
#pragma unroll
  for (int i = 0; i < 16; ++i) { acc0[i] = 0.f; acc1[i] = 0.f; }
  const bf16x8* pW = (const bf16x8*)Wt;
  for (int tap = 0; tap < 9; ++tap) {
    int ky = tap / 3, kx = tap % 3;
    int xg = xh * 32 + n + kx - 1;
    int xx = xg < 0 ? 1 : (xg > 63 ? 62 : xg);  // reflect pad=1
    int base = (ky * 64 + xx) * 128;
    int xs = xx & 15;
#pragma unroll
    for (int kk = 0; kk < 8; ++kk) {
      bf16x8 av = pW[(size_t)((tap * 8 + kk) * 4 + cb) * 64 + lane];
      bf16x8 bv = *(const bf16x8*)&lds[base + ((kk * 2 + hi) ^ xs) * 8];
      if (kk & 1) acc1 = __builtin_amdgcn_mfma_f32_32x32x16_bf16(av, bv, acc1, 0, 0, 0);
      else        acc0 = __builtin_amdgcn_mfma_f32_32x32x16_bf16(av, bv, acc0, 0, 0, 0);
    }
  }
  int x0 = xh * 32 + (lane & 31);
  int rowadd = 4 * (lane >> 5);
#pragma unroll
  for (int r = 0; r < 16; ++r) {
    int rowm = (r & 3) + 8 * (r >> 2) + rowadd;
    int co = cb * 32 + rowm;
    size_t o = ((size_t)(b * C_ + co)) * L_ + y * 64 + x0;
    float v = fmaxf(acc0[r] + acc1[r] + bias[co], 0.f);
    if (MODE == 0) {
      ((ushort*)outv)[o] = f2bf(v);
    } else {
      ((float*)outv)[o] = v + res[o];
    }
  }
}

// ---------------------------------------------------------------------------
extern "C" void kernel_launch(void* const* d_in, const int* in_sizes, int n_in,
                              void* d_out, int out_size, void* d_ws, size_t ws_size,
                              hipStream_t stream) {
  const float* noisy   = (const float*)d_in[0];
  const float* aux     = (const float*)d_in[1];
  const float* ln_g    = (const float*)d_in[2];
  const float* ln_b    = (const float*)d_in[3];
  const float* ipw     = (const float*)d_in[4];
  const float* cw      = (const float*)d_in[5];
  const float* cbv     = (const float*)d_in[6];
  const float* A_log   = (const float*)d_in[7];
  const float* dt_bias = (const float*)d_in[8];
  const float* Dp      = (const float*)d_in[9];
  const float* rmsw    = (const float*)d_in[10];
  const float* opw     = (const float*)d_in[11];
  const float* fw1     = (const float*)d_in[12];
  const float* fb1     = (const float*)d_in[13];
  const float* fw2     = (const float*)d_in[14];
  const float* fb2     = (const float*)d_in[15];
  float* out = (float*)d_out;
  float* ws  = (float*)d_ws;

  // Workspace layout (floats). Total ~27.6M floats ~= 110 MB.
  const size_t OFF_ZX   = 0;                            // 16384*644
  const size_t OFF_XBC  = OFF_ZX + 16384UL * 644;       // 16384*384
  const size_t OFF_SCN  = OFF_XBC + 16384UL * 384;      // 4,194,304: SC -> FF1(bf16)
  const size_t OFF_WT   = OFF_SCN + 4194304UL;          // 73,728: Wt1
  const size_t OFF_WO   = OFF_WT + 73728UL;             // 32,768: Woh+Wol
  const size_t OFF_CUM  = OFF_WT + 131072UL;            // 65,536: CUM
  const size_t OFF_YL   = OFF_CUM + 65536UL;            // 16384*256; Bn hi+lo early
  const size_t OFF_PC   = OFF_YL + 16384UL * 256;       // 1024
  const size_t OFF_WT2  = OFF_PC + 1024UL;              // 73,728: Wt2
  const size_t OFF_YRES = OFF_WT2 + 73728UL;            // 2,097,152: YRES

  float* ZX   = ws + OFF_ZX;
  float* XBC  = ws + OFF_XBC;
  float* SC   = ws + OFF_SCN;
  float* CUM  = ws + OFF_CUM;
  float* YL   = ws + OFF_YL;
  float* PC   = ws + OFF_PC;
  ushort* Bnh  = (ushort*)(ws + OFF_YL);           // in_proj weight frags (dead before YL)
  ushort* Bnl  = Bnh + 45056UL * 2;
  ushort* Wt1 = (ushort*)(ws + OFF_WT);            // tap-major conv1 weights
  ushort* Woh  = (ushort*)(ws + OFF_WO);           // out_proj weight frags
  ushort* Wol  = Woh + 32768UL;
  ushort* Wt2 = (ushort*)(ws + OFF_WT2);           // tap-major conv2 weights
  ushort* FF1 = (ushort*)(ws + OFF_SCN);           // bf16 (b,C,L), after SC dead
  float* YRES = ws + OFF_YRES;

  // 1) fused weight preps (in_proj, out_proj, conv1, conv2 — tap-major)
  wprep_all<<<560, 256, 0, stream>>>(ipw, Bnh, Bnl, opw, Woh, Wol, fw1, Wt1, fw2, Wt2);
  // 2) fused LN + in_proj GEMM -> ZX (32-px tiles, 2+ blocks/CU)
  ln_gemm1<<<dim3(128, 4), 512, 0, stream>>>(noisy, ln_g, ln_b, Bnh, Bnl, ZX);
  // 3) depthwise conv1d + silu -> XBC
  conv1d_silu<<<dim3(L_ / 16, B_), 384, 0, stream>>>(ZX, cw, cbv, XBC);
  // 4) chunked scan (CHUNK=64, LDS-broadcast staging)
  scan_passA<<<dim3(NCHUNK, NH, B_), 256, 0, stream>>>(XBC, ZX, dt_bias, A_log, YL, SC, PC, CUM);
  scan_passB<<<256, 256, 0, stream>>>(SC, PC);
  // 5) fused pass C (MFMA) + gate + RMSNorm + out_proj GEMM + transpose + residual
  //    (half-chunk blocks, 2 blocks/CU)
  passC_gate<<<dim3(NCHUNK * 2, B_), 512, 0, stream>>>(XBC, SC, CUM, Dp, YL, ZX,
                                                       rmsw, Woh, Wol, noisy, YRES);
  // 6) ff1 = relu(conv3x3(YRES)) — direct 9-tap implicit GEMM, bf16 out
  //    (x-half blocks, 2 blocks/CU)
  conv3x3_direct<0><<<dim3(128, 4), 256, 0, stream>>>(YRES, Wt1, fb1, nullptr, FF1, nullptr);
  // 7) out_y = YRES + relu(conv3x3(FF1)); z=1 blocks copy aux -> out[2M..)
  conv3x3_direct<1><<<dim3(128, 4, 2), 256, 0, stream>>>(FF1, Wt2, fb2, YRES, out, aux);
}

// Round 10
// 225.065 us; speedup vs baseline: 1.1133x; 1.1133x over previous
//
#include <hip/hip_runtime.h>
#include <cstddef>

// Problem constants (b=4, ch=128, h=w=64)
#define B_      4
#define C_      128
#define L_      4096      // h*w
#define DIN     256       // expand*ch
#define NH      4         // heads
#define HD      64        // head dim
#define DS      64        // d_state
#define CONVCH  384       // din + 2*ds
#define DPROJ   644       // 2*din + 2*ds + nh
#define CHUNK   64
#define NCHUNK  64        // L_/CHUNK

typedef short bf16x8 __attribute__((ext_vector_type(8)));
typedef float floatx16 __attribute__((ext_vector_type(16)));

__device__ __forceinline__ float siluf(float v) { return v / (1.f + __expf(-v)); }

__device__ __forceinline__ ushort f2bf(float v) {
  unsigned u = __float_as_uint(v);
  unsigned r = (u + 0x7fff + ((u >> 16) & 1)) >> 16;
  return (ushort)r;
}
__device__ __forceinline__ float bf2f(ushort h) {
  return __uint_as_float((unsigned)h << 16);
}

// split 8 fp32 into hi/lo bf16x8 fragments (3-term split-bf16 scheme)
__device__ __forceinline__ void split8(float4 v0, float4 v1, bf16x8& hi, bf16x8& lo) {
  float f[8] = {v0.x, v0.y, v0.z, v0.w, v1.x, v1.y, v1.z, v1.w};
#pragma unroll
  for (int j = 0; j < 8; ++j) {
    ushort h = f2bf(f[j]);
    hi[j] = (short)h;
    lo[j] = (short)f2bf(f[j] - bf2f(h));
  }
}

// ---------------------------------------------------------------------------
// wprep_all: fused weight prep — ipw (blocks 0..175), opw (176..303),
// fw1 conv weights (304..431), fw2 conv weights (432..559). Tap-major conv
// weights: Wt[((tap*8 + kk)*4 + cb)*512 + l*8 + j], k = ci, m = co.
__global__ __launch_bounds__(256) void wprep_all(
    const float* __restrict__ ipw, ushort* __restrict__ Bh, ushort* __restrict__ Bl,
    const float* __restrict__ opw, ushort* __restrict__ Oh, ushort* __restrict__ Ol,
    const float* __restrict__ fw1, ushort* __restrict__ Wt1,
    const float* __restrict__ fw2, ushort* __restrict__ Wt2) {
  int bi = blockIdx.x;
  int t = threadIdx.x;
  if (bi < 176) {
    int e = bi * 256 + t;
    int d = e >> 6;
    int c0 = (e & 63) * 2;
    int kk = c0 >> 4;
    int l = (d & 31) + 32 * ((c0 & 15) >> 3);
    int j = c0 & 7;
    size_t off = (((size_t)(d >> 5)) * 8 + kk) * 512 + l * 8 + j;
    float v0 = d < 644 ? ipw[(size_t)d * 128 + c0] : 0.f;
    float v1 = d < 644 ? ipw[(size_t)d * 128 + c0 + 1] : 0.f;
    ushort h0 = f2bf(v0), h1 = f2bf(v1);
    *(unsigned*)(Bh + off) = (unsigned)h0 | ((unsigned)h1 << 16);
    *(unsigned*)(Bl + off) = (unsigned)f2bf(v0 - bf2f(h0)) |
                             ((unsigned)f2bf(v1 - bf2f(h1)) << 16);
  } else if (bi < 304) {
    int e = (bi - 176) * 256 + t;  // 0..32767
    int d = e >> 8;
    int c = e & 255;
    size_t f = ((size_t)(d >> 5) * 16 + (c >> 4)) * 512 +
               ((d & 31) + 32 * ((c & 15) >> 3)) * 8 + (c & 7);
    float v = opw[(size_t)d * 256 + c];
    ushort h = f2bf(v);
    Oh[f] = h;
    Ol[f] = f2bf(v - bf2f(h));
  } else {
    const float* fw = bi < 432 ? fw1 : fw2;
    ushort* Wt = bi < 432 ? Wt1 : Wt2;
    int co = (bi - 304) & 127;  // 0..127
    int cb = co >> 5;
    for (int e = t; e < 1152; e += 256) {
      int tap = e >> 7;          // 0..8
      int ci = e & 127;          // 0..127
      int kk = ci >> 4, k16 = ci & 15;
      int l = (co & 31) + 32 * (k16 >> 3);
      int off = ((tap * 8 + kk) * 4 + cb) * 512 + l * 8 + (k16 & 7);
      Wt[off] = f2bf(fw[(size_t)co * 1152 + ci * 9 + tap]);
    }
  }
}

// ---------------------------------------------------------------------------
// ln_gemm1 v2: fused LayerNorm + in_proj GEMM, 32-px tiles for 2+ blocks/CU.
// grid (128, 4), block 512.
__global__ __launch_bounds__(512) void ln_gemm1(
    const float* __restrict__ noisy, const float* __restrict__ gamma,
    const float* __restrict__ beta,
    const ushort* __restrict__ Bh, const ushort* __restrict__ Bl,
    float* __restrict__ ZX) {
  int row = blockIdx.x, b = blockIdx.y;   // row = 32-px tile index (0..127)
  int t = threadIdx.x;                    // 0..511
  __shared__ float tile[32 * 129];              // 16.5 KB
  __shared__ float ps[16][32], pq[16][32];      // 4 KB
  __shared__ float smu[32], srs[32];
  __shared__ __align__(16) ushort AhL[4096];    // 8 KB
  __shared__ __align__(16) ushort AlL[4096];    // 8 KB
  int px = t & 31, cg = t >> 5;  // cg 0..15
  float s = 0.f, s2 = 0.f;
  const float* src = noisy + ((size_t)b * C_) * L_ + row * 32;
  for (int i = 0; i < 8; ++i) {
    int c = cg * 8 + i;
    float v = src[(size_t)c * L_ + px];
    tile[px * 129 + c] = v;
    s += v; s2 += v * v;
  }
  ps[cg][px] = s; pq[cg][px] = s2;
  __syncthreads();
  if (t < 32) {
    float a = 0.f, qq = 0.f;
#pragma unroll
    for (int g = 0; g < 16; ++g) { a += ps[g][t]; qq += pq[g][t]; }
    float mu = a * (1.f / 128.f);
    float var = qq * (1.f / 128.f) - mu * mu;
    smu[t] = mu;
    srs[t] = rsqrtf(var + 1e-5f);
  }
  __syncthreads();
  for (int idx = t; idx < 2048; idx += 512) {
    int p2 = idx >> 6;       // pixel within tile (0..31)
    int c0 = (idx & 63) * 2; // channel pair
    float v0 = (tile[p2 * 129 + c0] - smu[p2]) * srs[p2] * gamma[c0] + beta[c0];
    float v1 = (tile[p2 * 129 + c0 + 1] - smu[p2]) * srs[p2] * gamma[c0 + 1] + beta[c0 + 1];
    int kk = c0 >> 4;
    int l = p2 + 32 * ((c0 & 15) >> 3);
    int j = c0 & 7;  // even
    int off = kk * 512 + l * 8 + j;
    ushort h0 = f2bf(v0), h1 = f2bf(v1);
    *(unsigned*)(AhL + off) = (unsigned)h0 | ((unsigned)h1 << 16);
    *(unsigned*)(AlL + off) = (unsigned)f2bf(v0 - bf2f(h0)) |
                              ((unsigned)f2bf(v1 - bf2f(h1)) << 16);
  }
  __syncthreads();
  int wv = t >> 6, lane = t & 63;
  int db = wv & 1, bq = wv >> 1;  // bq 0..3
  int rowadd = 4 * (lane >> 5);
  for (int bn = bq; bn < 11; bn += 4) {
    floatx16 acc;
#pragma unroll
    for (int i = 0; i < 16; ++i) acc[i] = 0.f;
    size_t bbase = ((size_t)(bn * 2 + db) * 8) * 64 + lane;
    const bf16x8* pBh = (const bf16x8*)Bh + bbase;
    const bf16x8* pBl = (const bf16x8*)Bl + bbase;
#pragma unroll
    for (int kk = 0; kk < 8; ++kk) {
      bf16x8 ah = *(const bf16x8*)(AhL + kk * 512 + lane * 8);
      bf16x8 al = *(const bf16x8*)(AlL + kk * 512 + lane * 8);
      bf16x8 bh = pBh[kk * 64];
      bf16x8 bl = pBl[kk * 64];
      acc = __builtin_amdgcn_mfma_f32_32x32x16_bf16(ah, bh, acc, 0, 0, 0);
      acc = __builtin_amdgcn_mfma_f32_32x32x16_bf16(al, bh, acc, 0, 0, 0);
      acc = __builtin_amdgcn_mfma_f32_32x32x16_bf16(ah, bl, acc, 0, 0, 0);
    }
    int d = bn * 64 + db * 32 + (lane & 31);
    if (d < 644) {
#pragma unroll
      for (int r = 0; r < 16; ++r) {
        int rowm = (r & 3) + 8 * (r >> 2) + rowadd;
        int pix = row * 32 + rowm;
        ZX[((size_t)(b * L_ + pix)) * DPROJ + d] = acc[r];
      }
    }
  }
}

// ---------------------------------------------------------------------------
// K3: depthwise causal conv1d (k=5) + bias + silu; 16 outputs/thread.
__global__ __launch_bounds__(384) void conv1d_silu(
    const float* __restrict__ ZX, const float* __restrict__ cw,
    const float* __restrict__ cb, float* __restrict__ XBC) {
  int ch = threadIdx.x;
  int l0 = blockIdx.x * 16, b = blockIdx.y;
  const float* base = ZX + ((size_t)b * L_) * DPROJ + DIN + ch;
  float w0 = cw[ch * 5], w1 = cw[ch * 5 + 1], w2 = cw[ch * 5 + 2],
        w3 = cw[ch * 5 + 3], w4 = cw[ch * 5 + 4];
  float bias = cb[ch];
  float win[20];
#pragma unroll
  for (int i = 0; i < 20; ++i) {
    int ll = l0 - 4 + i;
    win[i] = ll >= 0 ? base[(size_t)ll * DPROJ] : 0.f;
  }
  float* dst = XBC + ((size_t)(b * L_ + l0)) * CONVCH + ch;
#pragma unroll
  for (int j = 0; j < 16; ++j) {
    float acc = bias + w0 * win[j] + w1 * win[j + 1] + w2 * win[j + 2] +
                w3 * win[j + 3] + w4 * win[j + 4];
    dst[(size_t)j * CONVCH] = siluf(acc);
  }
}

// ---------------------------------------------------------------------------
// scan_passA v2 (Mamba2 chunked-MFMA form): per (chunk,h,b):
//   la = A*cumsum(dt);  G = C·B^T (MFMA);  M[t][s] = exp(la_t-la_s)*dt_s (s<=t)
//   Y_intra = (G∘M)·X (MFMA);  S_chunk = (w∘X)^T·B (MFMA), w_s=exp(la63-la_s)dt_s
// Replaces the serial scan (was LDS-instruction-issue bound at ~41 us).
// grid (NCHUNK, NH, B_), block 256 (4 waves). LDS 52 KB -> 3 blocks/CU.
__global__ __launch_bounds__(256) void scan_passA(
    const float* __restrict__ XBC, const float* __restrict__ ZX,
    const float* __restrict__ dt_bias, const float* __restrict__ A_log,
    float* __restrict__ YL, float* __restrict__ SC, float* __restrict__ PC,
    float* __restrict__ CUM) {
  int chunk = blockIdx.x, h = blockIdx.y, b = blockIdx.z;
  int t = threadIdx.x;
  int wv = t >> 6, lane = t & 63;
  int bh = b * NH + h;
  int l0 = chunk * CHUNK;
  size_t pix0g = (size_t)b * L_ + l0;
  __shared__ float sB[64 * 68];    // [s][n] (padded stride 68)
  __shared__ float sC[64 * 68];    // [t][n] -> reused as sG [t][s]
  __shared__ float sXT[64 * 68];   // [p][s] (x transposed)
  __shared__ float sdt[64], sla[64], sw[64];

  // --- stage B, C, X^T ---
#pragma unroll
  for (int i = 0; i < 12; ++i) {
    int e = t + i * 256;          // 0..3071
    int reg = e >> 10;            // 0=B, 1=C, 2=X
    int idx2 = e & 1023;
    int row = idx2 >> 4, c4 = (idx2 & 15) * 4;
    const float* gsrc = XBC + (pix0g + row) * CONVCH;
    if (reg == 0) {
      *(float4*)&sB[row * 68 + c4] = *(const float4*)(gsrc + DIN + c4);
    } else if (reg == 1) {
      *(float4*)&sC[row * 68 + c4] = *(const float4*)(gsrc + DIN + DS + c4);
    } else {
      float4 xv = *(const float4*)(gsrc + h * HD + c4);
      sXT[(c4 + 0) * 68 + row] = xv.x;
      sXT[(c4 + 1) * 68 + row] = xv.y;
      sXT[(c4 + 2) * 68 + row] = xv.z;
      sXT[(c4 + 3) * 68 + row] = xv.w;
    }
  }
  // --- dt / la / cum / w (wave 0; lane = timestep) ---
  if (wv == 0) {
    float v = ZX[(pix0g + lane) * DPROJ + 640 + h] + dt_bias[h];
    float dt = v > 20.f ? v : log1pf(expf(v));
    float A = -expf(A_log[h]);
    float cdt = dt;
#pragma unroll
    for (int off = 1; off < 64; off <<= 1) {
      float u = __shfl_up(cdt, off);
      if (lane >= off) cdt += u;
    }
    float la = cdt * A;
    float la63 = __shfl(la, 63);
    float cum = expf(la);
    sdt[lane] = dt;
    sla[lane] = la;
    sw[lane] = expf(la63 - la) * dt;
    CUM[(size_t)bh * L_ + l0 + lane] = cum;
    if (lane == 63) PC[bh * NCHUNK + chunk] = cum;
  }
  __syncthreads();

  int l31 = lane & 31, lhi = lane >> 5;
  int rowadd = 4 * lhi;
  int ttile = wv >> 1, stile = wv & 1;

  // --- GEMM1: G[t][s] = sum_n C[t][n]*B[s][n] ---
  floatx16 acc;
#pragma unroll
  for (int i = 0; i < 16; ++i) acc[i] = 0.f;
#pragma unroll
  for (int kb = 0; kb < 4; ++kb) {
    const float* ap = &sC[(ttile * 32 + l31) * 68 + kb * 16 + lhi * 8];
    const float* bp = &sB[(stile * 32 + l31) * 68 + kb * 16 + lhi * 8];
    float4 a0 = *(const float4*)ap, a1 = *(const float4*)(ap + 4);
    float4 b0 = *(const float4*)bp, b1 = *(const float4*)(bp + 4);
    bf16x8 ah, al, bh, bl;
    split8(a0, a1, ah, al);
    split8(b0, b1, bh, bl);
    acc = __builtin_amdgcn_mfma_f32_32x32x16_bf16(ah, bh, acc, 0, 0, 0);
    acc = __builtin_amdgcn_mfma_f32_32x32x16_bf16(al, bh, acc, 0, 0, 0);
    acc = __builtin_amdgcn_mfma_f32_32x32x16_bf16(ah, bl, acc, 0, 0, 0);
  }
  __syncthreads();   // all GEMM1 reads of sC complete before overwrite

  // --- mask + write sG (aliases sC) ---
  float* sG = sC;
#pragma unroll
  for (int r = 0; r < 16; ++r) {
    int tt = ttile * 32 + (r & 3) + 8 * (r >> 2) + rowadd;
    int ss = stile * 32 + l31;
    float val = 0.f;
    if (ss <= tt) val = acc[r] * __expf(sla[tt] - sla[ss]) * sdt[ss];
    sG[tt * 68 + ss] = val;
  }
  __syncthreads();

  // --- GEMM2: Y[t][p] = sum_s G[t][s]*X[s][p] -> YL global ---
  {
    int ptile = stile;
    floatx16 acc2;
#pragma unroll
    for (int i = 0; i < 16; ++i) acc2[i] = 0.f;
#pragma unroll
    for (int kb = 0; kb < 4; ++kb) {
      const float* ap = &sG[(ttile * 32 + l31) * 68 + kb * 16 + lhi * 8];
      const float* bp = &sXT[(ptile * 32 + l31) * 68 + kb * 16 + lhi * 8];
      float4 a0 = *(const float4*)ap, a1 = *(const float4*)(ap + 4);
      float4 b0 = *(const float4*)bp, b1 = *(const float4*)(bp + 4);
      bf16x8 ah, al, bh, bl;
      split8(a0, a1, ah, al);
      split8(b0, b1, bh, bl);
      acc2 = __builtin_amdgcn_mfma_f32_32x32x16_bf16(ah, bh, acc2, 0, 0, 0);
      acc2 = __builtin_amdgcn_mfma_f32_32x32x16_bf16(al, bh, acc2, 0, 0, 0);
      acc2 = __builtin_amdgcn_mfma_f32_32x32x16_bf16(ah, bl, acc2, 0, 0, 0);
    }
#pragma unroll
    for (int r = 0; r < 16; ++r) {
      int tt = ttile * 32 + (r & 3) + 8 * (r >> 2) + rowadd;
      int p = ptile * 32 + l31;
      YL[(pix0g + tt) * DIN + h * HD + p] = acc2[r];
    }
  }

  // --- GEMM3: S[p][n] = sum_s (X[s][p]*w_s)*B[s][n] -> SC global ---
  {
    int p2tile = wv >> 1, ntile = wv & 1;
    floatx16 acc3;
#pragma unroll
    for (int i = 0; i < 16; ++i) acc3[i] = 0.f;
#pragma unroll
    for (int kb = 0; kb < 4; ++kb) {
      int s0 = kb * 16 + lhi * 8;
      const float* ap = &sXT[(p2tile * 32 + l31) * 68 + s0];
      float4 a0 = *(const float4*)ap, a1 = *(const float4*)(ap + 4);
      float4 w0 = *(const float4*)&sw[s0], w1 = *(const float4*)&sw[s0 + 4];
      a0.x *= w0.x; a0.y *= w0.y; a0.z *= w0.z; a0.w *= w0.w;
      a1.x *= w1.x; a1.y *= w1.y; a1.z *= w1.z; a1.w *= w1.w;
      int n = ntile * 32 + l31;
      float bf[8];
#pragma unroll
      for (int j = 0; j < 8; ++j) bf[j] = sB[(s0 + j) * 68 + n];
      float4 b0 = make_float4(bf[0], bf[1], bf[2], bf[3]);
      float4 b1 = make_float4(bf[4], bf[5], bf[6], bf[7]);
      bf16x8 ah, al, bh, bl;
      split8(a0, a1, ah, al);
      split8(b0, b1, bh, bl);
      acc3 = __builtin_amdgcn_mfma_f32_32x32x16_bf16(ah, bh, acc3, 0, 0, 0);
      acc3 = __builtin_amdgcn_mfma_f32_32x32x16_bf16(al, bh, acc3, 0, 0, 0);
      acc3 = __builtin_amdgcn_mfma_f32_32x32x16_bf16(ah, bl, acc3, 0, 0, 0);
    }
    float* scp = SC + ((size_t)bh * NCHUNK + chunk) * 4096;
#pragma unroll
    for (int r = 0; r < 16; ++r) {
      int p = p2tile * 32 + (r & 3) + 8 * (r >> 2) + rowadd;
      int n = ntile * 32 + l31;
      scp[p * 64 + n] = acc3[r];
    }
  }
}

// ---------------------------------------------------------------------------
// K6: element-parallel in-place scan over chunks: SC[c] <- exclusive prefix state.
__global__ __launch_bounds__(256) void scan_passB(
    float* __restrict__ SC, const float* __restrict__ PC) {
  int bh = blockIdx.x >> 4;
  int eg = blockIdx.x & 15;
  int e = eg * 256 + threadIdx.x;
  float h = 0.f;
#pragma unroll 8
  for (int c = 0; c < NCHUNK; ++c) {
    size_t idx = ((size_t)bh * NCHUNK + c) * 4096 + e;
    float s = SC[idx];
    float pcv = PC[bh * NCHUNK + c];
    SC[idx] = h;
    h = h * pcv + s;
  }
}

// ---------------------------------------------------------------------------
// passC_gate v3: half-chunk blocks (32 px) for 2 blocks/CU. grid (NCHUNK*2, B_),
// block 512 (8 waves).
__global__ __launch_bounds__(512) void passC_gate(
    const float* __restrict__ XBC, const float* __restrict__ SC,
    const float* __restrict__ CUM, const float* __restrict__ Dp,
    const float* __restrict__ YL, const float* __restrict__ ZX,
    const float* __restrict__ rmsw,
    const ushort* __restrict__ Oh, const ushort* __restrict__ Ol,
    const float* __restrict__ noisy, float* __restrict__ YRES) {
  __shared__ float yt[8192];                     // 32 KB: [32 px][256 ch]
  __shared__ __align__(16) ushort fr[16384];     // 32 KB: C-stage / frags / fp32 tile
  int hc = blockIdx.x, b = blockIdx.y;           // hc = half-chunk (0..127)
  int chunk = hc >> 1;
  int l0 = hc * 32;
  int t = threadIdx.x;                           // 0..511
  int wv = t >> 6, lane = t & 63;
  size_t pix0g = (size_t)b * L_ + l0;
  float* sCcf  = (float*)fr;        // [32 px][16 float4-slots] XOR-swizzled, 8 KB
  float* scumf = sCcf + 2048;       // [4 h][32 px], 0.5 KB

  // --- phase 0a: zreg prefetch, YL->yt, stage C + cum ---
  float4 zr[4];
  {
    int lp = t & 31, slot2 = t >> 5;  // slot2 0..15
#pragma unroll
    for (int it = 0; it < 2; ++it) {
      const float* z = ZX + (pix0g + it * 16 + slot2) * DPROJ;
      zr[it * 2]     = *(const float4*)(z + lp * 4);
      zr[it * 2 + 1] = *(const float4*)(z + 128 + lp * 4);
    }
  }
  for (int i = t; i < 2048; i += 512) {
    *(float4*)&yt[i * 4] = *(const float4*)&YL[pix0g * DIN + (size_t)i * 4];
  }
  {
    int px = t >> 4, slot = t & 15;   // px 0..31
    float4 cv = *(const float4*)(XBC + (pix0g + px) * CONVCH + DIN + DS + slot * 4);
    ((float4*)sCcf)[px * 16 + (slot ^ (px & 7))] = cv;
    if (t < 128) {
      int hh = t >> 5, px2 = t & 31;
      scumf[t] = CUM[((size_t)(b * NH + hh)) * L_ + l0 + px2];
    }
  }
  __syncthreads();

  // --- phase 0b: yt += x * D (skip term) ---
  {
    int px = t >> 4, c4 = (t & 15) * 4;
    const float* xs = XBC + (pix0g + px) * CONVCH;
#pragma unroll
    for (int hh = 0; hh < 4; ++hh) {
      float4 xv = *(const float4*)(xs + hh * HD + c4);
      float dv = Dp[hh];
      float* dst = &yt[px * 256 + hh * 64 + c4];
      dst[0] += xv.x * dv; dst[1] += xv.y * dv;
      dst[2] += xv.z * dv; dst[3] += xv.w * dv;
    }
  }
  __syncthreads();

  // --- phase 1: per-head inter-chunk GEMM Y += (C x S^T) * cum ---
  {
    int h1 = wv >> 1, ptile = wv & 1;
    int arow = lane & 31;             // px row 0..31
    const float* Sb = SC + (((size_t)(b * NH + h1)) * NCHUNK + chunk) * 4096 +
                      (size_t)(ptile * 32 + (lane & 31)) * 64 + (lane >> 5) * 8;
    const float4* av = (const float4*)sCcf + arow * 16;
    int s0 = (lane >> 5) * 2;
    floatx16 acc;
#pragma unroll
    for (int i = 0; i < 16; ++i) acc[i] = 0.f;
#pragma unroll
    for (int kk = 0; kk < 4; ++kk) {
      float4 b0 = *(const float4*)(Sb + kk * 16);
      float4 b1 = *(const float4*)(Sb + kk * 16 + 4);
      int sa = kk * 4 + s0;
      float4 a0 = av[sa ^ (arow & 7)];
      float4 a1 = av[(sa + 1) ^ (arow & 7)];
      bf16x8 ah, al, bh, bl;
      split8(a0, a1, ah, al);
      split8(b0, b1, bh, bl);
      acc = __builtin_amdgcn_mfma_f32_32x32x16_bf16(ah, bh, acc, 0, 0, 0);
      acc = __builtin_amdgcn_mfma_f32_32x32x16_bf16(al, bh, acc, 0, 0, 0);
      acc = __builtin_amdgcn_mfma_f32_32x32x16_bf16(ah, bl, acc, 0, 0, 0);
    }
    int col = h1 * 64 + ptile * 32 + (lane & 31);
    int radd = 4 * (lane >> 5);
#pragma unroll
    for (int r = 0; r < 16; ++r) {
      int px = (r & 3) + 8 * (r >> 2) + radd;   // 0..31
      yt[px * 256 + col] += acc[r] * scumf[h1 * 32 + px];
    }
  }
  __syncthreads();   // yt complete; sCcf dead -> fr reusable as frags

  // --- phase 2: gating + RMSNorm -> bf16 hi/lo frags in fr (z from zr) ---
  ushort* AhL = fr;            // 16 KB
  ushort* AlL = fr + 8192;     // 16 KB
  {
    int lp = t & 31;
    int slot = t >> 5;           // 0..15
    float4 w0 = *(const float4*)(rmsw + lp * 4);
    float4 w1 = *(const float4*)(rmsw + 128 + lp * 4);
#pragma unroll
    for (int it = 0; it < 2; ++it) {
      int pl = it * 16 + slot;   // 0..31
      const float* y = &yt[pl * 256];
      float4 y0 = *(const float4*)(y + lp * 4);
      float4 y1 = *(const float4*)(y + 128 + lp * 4);
      float4 z0 = zr[it * 2];
      float4 z1 = zr[it * 2 + 1];
      float g[8];
      g[0] = y0.x * siluf(z0.x); g[1] = y0.y * siluf(z0.y);
      g[2] = y0.z * siluf(z0.z); g[3] = y0.w * siluf(z0.w);
      g[4] = y1.x * siluf(z1.x); g[5] = y1.y * siluf(z1.y);
      g[6] = y1.z * siluf(z1.z); g[7] = y1.w * siluf(z1.w);
      float ss = 0.f;
#pragma unroll
      for (int j = 0; j < 8; ++j) ss += g[j] * g[j];
      ss += __shfl_xor(ss, 16);
      ss += __shfl_xor(ss, 8);
      ss += __shfl_xor(ss, 4);
      ss += __shfl_xor(ss, 2);
      ss += __shfl_xor(ss, 1);
      float rs = rsqrtf(ss * (1.f / 256.f) + 1e-5f);
      float o[8];
      o[0] = g[0] * rs * w0.x; o[1] = g[1] * rs * w0.y;
      o[2] = g[2] * rs * w0.z; o[3] = g[3] * rs * w0.w;
      o[4] = g[4] * rs * w1.x; o[5] = g[5] * rs * w1.y;
      o[6] = g[6] * rs * w1.z; o[7] = g[7] * rs * w1.w;
#pragma unroll
      for (int grp = 0; grp < 2; ++grp) {
        int d = grp * 128 + lp * 4;
        int off = (d >> 4) * 512 + (pl + 32 * ((d & 15) >> 3)) * 8 + (d & 7);
        ushort h0 = f2bf(o[grp*4+0]), h1 = f2bf(o[grp*4+1]);
        ushort h2 = f2bf(o[grp*4+2]), h3 = f2bf(o[grp*4+3]);
        uint2 hv, lv;
        hv.x = (unsigned)h0 | ((unsigned)h1 << 16);
        hv.y = (unsigned)h2 | ((unsigned)h3 << 16);
        lv.x = (unsigned)f2bf(o[grp*4+0] - bf2f(h0)) | ((unsigned)f2bf(o[grp*4+1] - bf2f(h1)) << 16);
        lv.y = (unsigned)f2bf(o[grp*4+2] - bf2f(h2)) | ((unsigned)f2bf(o[grp*4+3] - bf2f(h3)) << 16);
        *(uint2*)(AhL + off) = hv;
        *(uint2*)(AlL + off) = lv;
      }
    }
  }
  __syncthreads();

  // --- phase 3: out_proj GEMM (waves 0-3; M=32, N=128, K=256) ---
  floatx16 acc;
#pragma unroll
  for (int i = 0; i < 16; ++i) acc[i] = 0.f;
  int bn = wv >> 1, db = wv & 1;
  int rowadd = 4 * (lane >> 5);
  if (wv < 4) {
    const bf16x8* pBh = (const bf16x8*)Oh;
    const bf16x8* pBl = (const bf16x8*)Ol;
    size_t bbase = ((size_t)(bn * 2 + db) * 16) * 64 + lane;
#pragma unroll
    for (int kk = 0; kk < 16; ++kk) {
      bf16x8 ah = *(const bf16x8*)(AhL + kk * 512 + lane * 8);
      bf16x8 al = *(const bf16x8*)(AlL + kk * 512 + lane * 8);
      bf16x8 bh = pBh[bbase + (size_t)kk * 64];
      bf16x8 bl = pBl[bbase + (size_t)kk * 64];
      acc = __builtin_amdgcn_mfma_f32_32x32x16_bf16(ah, bh, acc, 0, 0, 0);
      acc = __builtin_amdgcn_mfma_f32_32x32x16_bf16(al, bh, acc, 0, 0, 0);
      acc = __builtin_amdgcn_mfma_f32_32x32x16_bf16(ah, bl, acc, 0, 0, 0);
    }
  }
  __syncthreads();   // frag reads complete -> fr reusable as fp32 tile

  // --- phase 4: transpose via LDS, residual add, write YRES (b,C,L) ---
  float* tile = (float*)fr;    // 32 px x 129 fp32 = 16.5 KB
  if (wv < 4) {
#pragma unroll
    for (int r = 0; r < 16; ++r) {
      int rowp = (r & 3) + 8 * (r >> 2) + rowadd;     // 0..31
      int col = bn * 64 + db * 32 + (lane & 31);      // 0..127
      tile[rowp * 129 + col] = acc[r];
    }
  }
  __syncthreads();
  for (int idx = t; idx < 4096; idx += 512) {
    int c = idx >> 5, px = idx & 31;
    size_t o = ((size_t)(b * C_ + c)) * L_ + l0 + px;
    YRES[o] = noisy[o] + tile[px * 129 + c];
  }
}

// ---------------------------------------------------------------------------
// conv3x3_direct: 3x3 reflect conv as 9-tap implicit GEMM, K=ci per tap.
// (round-8 proven version: grid (64,4[,2]), block 512, 8 waves = 4cb x 2nb)
// MODE 0: input fp32 (YRES), output bf16 = relu(conv+bias) (FF1).
// MODE 1: input bf16 (FF1), output fp32 = res + relu(conv+bias);
//         grid.z==1 blocks instead copy aux -> out[2M..4M) (folded memcpy).
template <int MODE>
__global__ __launch_bounds__(512) void conv3x3_direct(
    const void* __restrict__ inv, const ushort* __restrict__ Wt,
    const float* __restrict__ bias, const float* __restrict__ res,
    void* __restrict__ outv, const float* __restrict__ aux) {
  int y = blockIdx.x, b = blockIdx.y;
  int t = threadIdx.x;
  if (MODE == 1 && blockIdx.z == 1) {
    // aux passthrough: 2,097,152 floats over 256 blocks x 512 threads
    const float4* s = (const float4*)aux;
    float4* d = (float4*)((float*)outv + 2097152);
    int base = (b * 64 + y) * 512 + t;
#pragma unroll
    for (int k = 0; k < 4; ++k) d[base + k * 131072] = s[base + k * 131072];
    return;
  }
  __shared__ __align__(16) ushort lds[3 * 64 * 128];  // 48 KB
  int lane = t & 63;
  int wv = t >> 6;
  int ry[3];
  ry[0] = y == 0 ? 1 : y - 1;
  ry[1] = y;
  ry[2] = y == 63 ? 62 : y + 1;
  {
    int x = lane;
    for (int u = wv; u < 48; u += 8) {
      int r = u / 16;
      int cib = u % 16;
      int ci0 = cib * 8;
      ushort vals[8];
#pragma unroll
      for (int j = 0; j < 8; ++j) {
        size_t src = ((size_t)(b * C_ + ci0 + j)) * L_ + ry[r] * 64 + x;
        if (MODE == 0) vals[j] = f2bf(((const float*)inv)[src]);
        else           vals[j] = ((const ushort*)inv)[src];
      }
      int idx = (r * 64 + x) * 128 + (cib ^ (x & 15)) * 8;
      *(int4*)&lds[idx] = *(int4*)vals;
    }
  }
  __syncthreads();
  int cb = wv >> 1, nb = wv & 1;
  int n = lane & 31, hi = lane >> 5;
  floatx16 acc0, acc1;
#pragma unroll
  for (int i = 0; i < 16; ++i) { acc0[i] = 0.f; acc1[i] = 0.f; }
  const bf16x8* pW = (const bf16x8*)Wt;
  for (int tap = 0; tap < 9; ++tap) {
    int ky = tap / 3, kx = tap % 3;
    int xg = nb * 32 + n + kx - 1;
    int xx = xg < 0 ? 1 : (xg > 63 ? 62 : xg);  // reflect pad=1
    int base = (ky * 64 + xx) * 128;
    int xs = xx & 15;
#pragma unroll
    for (int kk = 0; kk < 8; ++kk) {
      bf16x8 av = pW[(size_t)((tap * 8 + kk) * 4 + cb) * 64 + lane];
      bf16x8 bv = *(const bf16x8*)&lds[base + ((kk * 2 + hi) ^ xs) * 8];
      if (kk & 1) acc1 = __builtin_amdgcn_mfma_f32_32x32x16_bf16(av, bv, acc1, 0, 0, 0);
      else        acc0 = __builtin_amdgcn_mfma_f32_32x32x16_bf16(av, bv, acc0, 0, 0, 0);
    }
  }
  int x0 = nb * 32 + (lane & 31);
  int rowadd = 4 * (lane >> 5);
#pragma unroll
  for (int r = 0; r < 16; ++r) {
    int rowm = (r & 3) + 8 * (r >> 2) + rowadd;
    int co = cb * 32 + rowm;
    size_t o = ((size_t)(b * C_ + co)) * L_ + y * 64 + x0;
    float v = fmaxf(acc0[r] + acc1[r] + bias[co], 0.f);
    if (MODE == 0) {
      ((ushort*)outv)[o] = f2bf(v);
    } else {
      ((float*)outv)[o] = v + res[o];
    }
  }
}

// ---------------------------------------------------------------------------
extern "C" void kernel_launch(void* const* d_in, const int* in_sizes, int n_in,
                              void* d_out, int out_size, void* d_ws, size_t ws_size,
                              hipStream_t stream) {
  const float* noisy   = (const float*)d_in[0];
  const float* aux     = (const float*)d_in[1];
  const float* ln_g    = (const float*)d_in[2];
  const float* ln_b    = (const float*)d_in[3];
  const float* ipw     = (const float*)d_in[4];
  const float* cw      = (const float*)d_in[5];
  const float* cbv     = (const float*)d_in[6];
  const float* A_log   = (const float*)d_in[7];
  const float* dt_bias = (const float*)d_in[8];
  const float* Dp      = (const float*)d_in[9];
  const float* rmsw    = (const float*)d_in[10];
  const float* opw     = (const float*)d_in[11];
  const float* fw1     = (const float*)d_in[12];
  const float* fb1     = (const float*)d_in[13];
  const float* fw2     = (const float*)d_in[14];
  const float* fb2     = (const float*)d_in[15];
  float* out = (float*)d_out;
  float* ws  = (float*)d_ws;

  // Workspace layout (floats). Total ~27.6M floats ~= 110 MB.
  const size_t OFF_ZX   = 0;                            // 16384*644
  const size_t OFF_XBC  = OFF_ZX + 16384UL * 644;       // 16384*384
  const size_t OFF_SCN  = OFF_XBC + 16384UL * 384;      // 4,194,304: SC -> FF1(bf16)
  const size_t OFF_WT   = OFF_SCN + 4194304UL;          // 73,728: Wt1
  const size_t OFF_WO   = OFF_WT + 73728UL;             // 32,768: Woh+Wol
  const size_t OFF_CUM  = OFF_WT + 131072UL;            // 65,536: CUM
  const size_t OFF_YL   = OFF_CUM + 65536UL;            // 16384*256; Bn hi+lo early
  const size_t OFF_PC   = OFF_YL + 16384UL * 256;       // 1024
  const size_t OFF_WT2  = OFF_PC + 1024UL;              // 73,728: Wt2
  const size_t OFF_YRES = OFF_WT2 + 73728UL;            // 2,097,152: YRES

  float* ZX   = ws + OFF_ZX;
  float* XBC  = ws + OFF_XBC;
  float* SC   = ws + OFF_SCN;
  float* CUM  = ws + OFF_CUM;
  float* YL   = ws + OFF_YL;
  float* PC   = ws + OFF_PC;
  ushort* Bnh  = (ushort*)(ws + OFF_YL);           // in_proj weight frags (dead before YL)
  ushort* Bnl  = Bnh + 45056UL * 2;
  ushort* Wt1 = (ushort*)(ws + OFF_WT);            // tap-major conv1 weights
  ushort* Woh  = (ushort*)(ws + OFF_WO);           // out_proj weight frags
  ushort* Wol  = Woh + 32768UL;
  ushort* Wt2 = (ushort*)(ws + OFF_WT2);           // tap-major conv2 weights
  ushort* FF1 = (ushort*)(ws + OFF_SCN);           // bf16 (b,C,L), after SC dead
  float* YRES = ws + OFF_YRES;

  // 1) fused weight preps (in_proj, out_proj, conv1, conv2 — tap-major)
  wprep_all<<<560, 256, 0, stream>>>(ipw, Bnh, Bnl, opw, Woh, Wol, fw1, Wt1, fw2, Wt2);
  // 2) fused LN + in_proj GEMM -> ZX (32-px tiles, 2+ blocks/CU)
  ln_gemm1<<<dim3(128, 4), 512, 0, stream>>>(noisy, ln_g, ln_b, Bnh, Bnl, ZX);
  // 3) depthwise conv1d + silu -> XBC
  conv1d_silu<<<dim3(L_ / 16, B_), 384, 0, stream>>>(ZX, cw, cbv, XBC);
  // 4) chunked scan pass A — Mamba2 MFMA form (G=C·B^T, mask, Y=(G∘M)X, S=(wX)^T·B)
  scan_passA<<<dim3(NCHUNK, NH, B_), 256, 0, stream>>>(XBC, ZX, dt_bias, A_log, YL, SC, PC, CUM);
  scan_passB<<<256, 256, 0, stream>>>(SC, PC);
  // 5) fused pass C (MFMA) + gate + RMSNorm + out_proj GEMM + transpose + residual
  //    (half-chunk blocks, 2 blocks/CU)
  passC_gate<<<dim3(NCHUNK * 2, B_), 512, 0, stream>>>(XBC, SC, CUM, Dp, YL, ZX,
                                                       rmsw, Woh, Wol, noisy, YRES);
  // 6) ff1 = relu(conv3x3(YRES)) — direct 9-tap implicit GEMM, bf16 out
  conv3x3_direct<0><<<dim3(64, 4), 512, 0, stream>>>(YRES, Wt1, fb1, nullptr, FF1, nullptr);
  // 7) out_y = YRES + relu(conv3x3(FF1)); z=1 blocks copy aux -> out[2M..)
  conv3x3_direct<1><<<dim3(64, 4, 2), 512, 0, stream>>>(FF1, Wt2, fb2, YRES, out, aux);
}